// Round 11
// baseline (566.266 us; speedup 1.0000x reference)
//
#include <hip/hip_runtime.h>
#include <stdint.h>

// B=8, T=4096, C=1024, NH=64, HD=16. M = B*T = 32768.

typedef __attribute__((ext_vector_type(8))) __bf16 bf16x8;
typedef __attribute__((ext_vector_type(4))) float f32x4;
typedef __attribute__((ext_vector_type(4))) unsigned int u32x4;
typedef __attribute__((ext_vector_type(4))) unsigned short u16x4;

#define AS1 __attribute__((address_space(1)))
#define AS3 __attribute__((address_space(3)))

__device__ __forceinline__ unsigned short f2bf(float f) {
  unsigned int u = __builtin_bit_cast(unsigned int, f);
  u += 0x7FFFu + ((u >> 16) & 1u);
  return (unsigned short)(u >> 16);
}

__device__ __forceinline__ void gl_lds16(const unsigned short* g, unsigned short* l) {
  __builtin_amdgcn_global_load_lds((const AS1 unsigned int*)g, (AS3 unsigned int*)l, 16, 0, 0);
}

// ---------------- fp32 -> bf16 converts ----------------
__global__ __launch_bounds__(256)
void cvt_x(const float* __restrict__ src, unsigned short* __restrict__ dst, int n4) {
  int i = blockIdx.x * blockDim.x + threadIdx.x;
  const int stride = gridDim.x * blockDim.x;
  for (; i < n4; i += stride) {
    f32x4 v = *(const f32x4*)(src + (size_t)i * 4);
    u16x4 o;
    o.x = f2bf(v.x); o.y = f2bf(v.y); o.z = f2bf(v.z); o.w = f2bf(v.w);
    *(u16x4*)(dst + (size_t)i * 4) = o;
  }
}

// Repack all four 1024x1024 weights into MFMA-fragment order (r4-validated):
// per weight, block f = n16*32 + ks32 (1KB each); lane l holds
// W[n16*16 + (l&15)][ks32*32 + (l>>4)*8 .. +8].
__global__ __launch_bounds__(256)
void cvt_w(const float* __restrict__ w0, const float* __restrict__ w1,
           const float* __restrict__ w2, const float* __restrict__ w3,
           unsigned short* __restrict__ dst) {
  const int g = blockIdx.x * 256 + threadIdx.x;   // 0..524287
  const int w = g >> 17;
  const int r = g & 131071;
  const int f = r >> 6;                           // n16*32 + ks32
  const int l = r & 63;
  const int n = (f >> 5) * 16 + (l & 15);
  const int k = (f & 31) * 32 + (l >> 4) * 8;
  const float* ws[4] = {w0, w1, w2, w3};
  const float* src = ws[w] + (size_t)n * 1024 + k;
  f32x4 v0 = *(const f32x4*)src;
  f32x4 v1 = *(const f32x4*)(src + 4);
  u16x4 a, b;
  a.x = f2bf(v0.x); a.y = f2bf(v0.y); a.z = f2bf(v0.z); a.w = f2bf(v0.w);
  b.x = f2bf(v1.x); b.y = f2bf(v1.y); b.z = f2bf(v1.z); b.w = f2bf(v1.w);
  unsigned short* o = dst + (size_t)g * 8;
  *(u16x4*)o = a;
  *(u16x4*)(o + 4) = b;
}

// ---------------- BARRIER-FREE pipelined 128x128 bf16 GEMM ----------------
// r10 structure, but A staging made WAVE-PRIVATE: each wave stages its own
// 64 rows into a private 3x4KB LDS ring -> ZERO s_barrier in the K-loop.
// All hazards wave-local:
//  RAW: iter t-1's vmcnt(8) leaves only {stage(t+2), loadB(t)} outstanding
//       -> stage(t), stage(t+1) landed before iter t's ds_reads.
//       Prologue vmcnt(12) covers t=0.
//  WAR: lgkmcnt(0)+sched_barrier after ds_reads, before stage(t+3) is issued
//       into the ring slot just read (data already in regs).
//  B:   iter t's vmcnt(8) (after issuing stage(t+3)+loadB(t+1)) completes
//       loadB(t).  Tail ledger: t=29,30 -> vmcnt(4); t=31 -> vmcnt(0).
// Same XOR swizzle as r10 within the private buffer (2-way = free).
// out[m][n] = sum_k A[m][k] * W[n][k] + bias[n]
// KIND 0: fused QKV, N=3072; KIND 1: proj, N=1024 (fp32 out).
template<int KIND>
__global__ __launch_bounds__(256, 3)
void gemm_pipe(const unsigned short* __restrict__ A,
               const unsigned short* __restrict__ Wf,
               const float* __restrict__ b0, const float* __restrict__ b1,
               const float* __restrict__ b2,
               unsigned short* __restrict__ oq, unsigned short* __restrict__ okT,
               unsigned short* __restrict__ ovT, float* __restrict__ of)
{
  __shared__ __align__(16) unsigned short lds[24576];   // 4 waves x 3 bufs x 4KB

  const int tid  = threadIdx.x;
  const int lane = tid & 63;
  const int wid  = tid >> 6;

  // XCD-aware bijective order (r4): per XCD, (col-group) x (32 A-panels) x (8 cols).
  const int flat  = blockIdx.x;
  const int xcd   = flat & 7;
  const int i     = flat >> 3;
  const int bcg   = i >> 8;
  const int r     = i & 255;
  const int panel = r >> 3;
  const int c     = r & 7;
  const int brow  = (xcd * 32 + panel) * 128;
  const int bcol  = (bcg * 8 + c) * 128;

  const int wm = (wid >> 1) * 64;       // wave tile 64x64
  const int wn = (wid & 1) * 64;
  const int fr = lane & 15;
  const int fg = lane >> 4;

  // Wave-private A staging: instr s covers rows wm + s*16 + (lane>>2);
  // dst 16B-slot = lane&3 (linear); src slot = (lane&3) ^ ((row>>1)&3)
  //  = (lane&3) ^ ((lane>>3)&3)  [s*16 contributes 0 mod 4 after >>1].
  const int scol = ((lane & 3) ^ ((lane >> 3) & 3)) << 3;
  const unsigned short* a_src =
      A + (size_t)(brow + wm + (lane >> 2)) * 1024 + scol;
  unsigned short* wave_lds = lds + wid * 6144;   // private 3-buffer ring

  // A-frag read: frag mt: row_local = mt*16+fr, slot = fg ^ ((fr>>1)&3).
  const unsigned short* aRd = wave_lds + fr * 32 + ((fg ^ ((fr >> 1) & 3)) << 3);

  // B fragment pointer: frag block = ((bcol+wn)>>4 + nt)*32 + t, 1KB/block, 16B/lane.
  const unsigned short* wfp = Wf + ((size_t)((bcol + wn) >> 4) * 32) * 512 + lane * 8;

  const f32x4 fz = {0.f, 0.f, 0.f, 0.f};
  f32x4 acc[4][4];
  #pragma unroll
  for (int mt = 0; mt < 4; ++mt)
    #pragma unroll
    for (int nt = 0; nt < 4; ++nt) acc[mt][nt] = fz;

  auto stage = [&](int t, int buf) {            // 4KB: 64 rows x 32 k
    const unsigned short* g = a_src + t * 32;
    unsigned short* d = wave_lds + buf * 2048;
    gl_lds16(g,          d);
    gl_lds16(g + 16384,  d + 512);
    gl_lds16(g + 32768,  d + 1024);
    gl_lds16(g + 49152,  d + 1536);
  };
  auto loadB = [&](int t, bf16x8 (&dst)[4]) {
    #pragma unroll
    for (int nt = 0; nt < 4; ++nt)
      dst[nt] = __builtin_bit_cast(bf16x8,
        *(const u32x4*)(wfp + (size_t)t * 512 + (size_t)nt * 16384));
  };

  bf16x8 brgA[4], brgB[4];

  // prologue: stage(0..2) into bufs 0..2 (12 loads) + loadB(0) (4 loads);
  // vmcnt(12) -> stage(0) landed; leaves stage(1),stage(2),loadB(0).
  stage(0, 0); stage(1, 1); stage(2, 2);
  loadB(0, brgA);
  asm volatile("s_waitcnt vmcnt(12)" ::: "memory");
  __builtin_amdgcn_sched_barrier(0);

  auto body = [&](int t, bf16x8 (&bc_)[4], bf16x8 (&bn_)[4]) {
    const unsigned short* Lb = aRd + (t % 3) * 2048;
    bf16x8 af[4];
    #pragma unroll
    for (int mt = 0; mt < 4; ++mt)
      af[mt] = __builtin_bit_cast(bf16x8, *(const u32x4*)(Lb + mt * 512));
    asm volatile("s_waitcnt lgkmcnt(0)" ::: "memory");   // frags in regs (WAR fence)
    __builtin_amdgcn_sched_barrier(0);
    if (t + 3 < 32) stage(t + 3, t % 3);                 // refill just-read slot
    if (t + 1 < 32) loadB(t + 1, bn_);                   // next B frags -> regs
    // steady: leave stage(t+3)[4]+loadB(t+1)[4]=8; forces loadB(t), stage(t+1).
    if (t <= 28)      asm volatile("s_waitcnt vmcnt(8)" ::: "memory");
    else if (t <= 30) asm volatile("s_waitcnt vmcnt(4)" ::: "memory");
    else              asm volatile("s_waitcnt vmcnt(0)" ::: "memory");
    __builtin_amdgcn_sched_barrier(0);
    __builtin_amdgcn_s_setprio(1);
    #pragma unroll
    for (int mt = 0; mt < 4; ++mt)
      #pragma unroll
      for (int nt = 0; nt < 4; ++nt)
        acc[mt][nt] = __builtin_amdgcn_mfma_f32_16x16x32_bf16(af[mt], bc_[nt], acc[mt][nt], 0, 0, 0);
    __builtin_amdgcn_s_setprio(0);
  };

  for (int t = 0; t < 32; t += 2) {   // static parity -> brgA/brgB never runtime-indexed
    body(t,     brgA, brgB);
    body(t + 1, brgB, brgA);
  }

  // ---------------- epilogue ----------------
  const int sec = (KIND == 0) ? (bcol >> 10) : 0;
  const float* bias = (KIND == 1) ? b0 : (sec == 0 ? b0 : (sec == 1 ? b1 : b2));

  #pragma unroll
  for (int nt = 0; nt < 4; ++nt) {
    const int n_glob = bcol + wn + nt * 16 + fr;
    const int nn = (KIND == 0) ? (n_glob & 1023) : n_glob;
    const float bv = bias[nn];
    #pragma unroll
    for (int mt = 0; mt < 4; ++mt) {
      const int m0 = brow + wm + mt * 16 + fg * 4;
      float vals[4];
      #pragma unroll
      for (int r2 = 0; r2 < 4; ++r2) vals[r2] = acc[mt][nt][r2] + bv;

      if (KIND == 0 && sec <= 1) {
        // softmax over the 16 columns (one head's HD), per row.
        // No max-subtraction: |q| <= ~6 -> exp safe in fp32 (validated r9/r10).
        #pragma unroll
        for (int r2 = 0; r2 < 4; ++r2) {
          float e = __expf(vals[r2]);
          float sm = e;
          #pragma unroll
          for (int s = 1; s < 16; s <<= 1) sm += __shfl_xor(sm, s, 64);
          vals[r2] = e * __builtin_amdgcn_rcpf(sm);
        }
      }

      if (KIND == 1) {
        #pragma unroll
        for (int r2 = 0; r2 < 4; ++r2)
          of[(size_t)(m0 + r2) * 1024 + n_glob] = vals[r2];
      } else if (sec == 0) {
        #pragma unroll
        for (int r2 = 0; r2 < 4; ++r2)
          oq[(size_t)(m0 + r2) * 1024 + nn] = f2bf(vals[r2]);
      } else {
        // transposed per head: dst[((b*64+h)*16+d)*4096 + t]
        unsigned short* o = (sec == 1) ? okT : ovT;
        const int bb = m0 >> 12;
        const int t0 = m0 & 4095;
        const int hh = nn >> 4;
        const int dd = nn & 15;
        u16x4 pk;
        pk.x = f2bf(vals[0]); pk.y = f2bf(vals[1]);
        pk.z = f2bf(vals[2]); pk.w = f2bf(vals[3]);
        *(u16x4*)&o[(((size_t)bb * 64 + hh) * 16 + dd) * 4096 + t0] = pk;
      }
    }
  }
}

// ---------------- per-head linear-attention middle ----------------
__global__ __launch_bounds__(256)
void attn_kernel(const unsigned short* __restrict__ qb,
                 const unsigned short* __restrict__ kT,
                 const unsigned short* __restrict__ vT,
                 unsigned short* __restrict__ yb)
{
  const int head = blockIdx.x;           // b*64 + h
  const int tid  = threadIdx.x;
  const int lane = tid & 63;
  const int wid  = tid >> 6;
  const int fr   = lane & 15;
  const int fg   = lane >> 4;

  const unsigned short* kTh = kT + (size_t)head * 16 * 4096;
  const unsigned short* vTh = vT + (size_t)head * 16 * 4096;

  const u32x4 uz = {0u, 0u, 0u, 0u};
  const f32x4 fz = {0.f, 0.f, 0.f, 0.f};
  const u32x4 uo = {0x3F803F80u, 0x3F803F80u, 0x3F803F80u, 0x3F803F80u};
  const bf16x8 ones = __builtin_bit_cast(bf16x8, uo);

  f32x4 cctx = fz, ckc = fz;
  #pragma unroll 4
  for (int t0 = wid * 1024; t0 < (wid + 1) * 1024; t0 += 32) {
    bf16x8 ak = __builtin_bit_cast(bf16x8, *(const u32x4*)&kTh[(size_t)fr * 4096 + t0 + fg * 8]);
    bf16x8 bv = __builtin_bit_cast(bf16x8, *(const u32x4*)&vTh[(size_t)fr * 4096 + t0 + fg * 8]);
    cctx = __builtin_amdgcn_mfma_f32_16x16x32_bf16(ak, bv, cctx, 0, 0, 0);
    ckc  = __builtin_amdgcn_mfma_f32_16x16x32_bf16(ak, ones, ckc, 0, 0, 0);
  }

  __shared__ float red[4][16][16];
  __shared__ float kcr[4][16];
  __shared__ float ctxf[16][16];
  __shared__ float kcf[16];

  #pragma unroll
  for (int r = 0; r < 4; ++r) red[wid][fg * 4 + r][fr] = cctx[r];
  if (fr == 0) {
    #pragma unroll
    for (int r = 0; r < 4; ++r) kcr[wid][fg * 4 + r] = ckc[r];
  }
  __syncthreads();
  {
    const int d = tid >> 4, e = tid & 15;
    ctxf[d][e] = red[0][d][e] + red[1][d][e] + red[2][d][e] + red[3][d][e];
    if (tid < 16) kcf[tid] = kcr[0][tid] + kcr[1][tid] + kcr[2][tid] + kcr[3][tid];
  }
  __syncthreads();

  bf16x8 bctx = __builtin_bit_cast(bf16x8, uz);
  bf16x8 bkc  = __builtin_bit_cast(bf16x8, uz);
  if (fg < 2) {
    #pragma unroll
    for (int j = 0; j < 8; ++j) {
      const int d = fg * 8 + j;
      bctx[j] = (__bf16)ctxf[d][fr];
      bkc[j]  = (__bf16)kcf[d];
    }
  }

  const int b = head >> 6;
  const int h = head & 63;
  const size_t qbase = (size_t)b * 4096 * 1024 + (size_t)h * 16;

  for (int step = 0; step < 64; ++step) {
    const int t0 = step * 64 + wid * 16;
    bf16x8 af = __builtin_bit_cast(bf16x8, uz);
    if (fg < 2)
      af = __builtin_bit_cast(bf16x8, *(const u32x4*)&qb[qbase + (size_t)(t0 + fr) * 1024 + fg * 8]);
    f32x4 cy = __builtin_amdgcn_mfma_f32_16x16x32_bf16(af, bctx, fz, 0, 0, 0);
    f32x4 cd = __builtin_amdgcn_mfma_f32_16x16x32_bf16(af, bkc,  fz, 0, 0, 0);
    #pragma unroll
    for (int r = 0; r < 4; ++r) {
      const int t = t0 + fg * 4 + r;
      const float yv = cy[r] * __builtin_amdgcn_rcpf(cd[r]);
      yb[qbase + (size_t)t * 1024 + fr] = f2bf(yv);
    }
  }
}

// ---------------- launch ----------------
extern "C" void kernel_launch(void* const* d_in, const int* in_sizes, int n_in,
                              void* d_out, int out_size, void* d_ws, size_t ws_size,
                              hipStream_t stream)
{
  (void)in_sizes; (void)n_in; (void)out_size; (void)ws_size;
  const float* x  = (const float*)d_in[0];
  const float* Wq = (const float*)d_in[1];
  const float* bq = (const float*)d_in[2];
  const float* Wk = (const float*)d_in[3];
  const float* bk = (const float*)d_in[4];
  const float* Wv = (const float*)d_in[5];
  const float* bv = (const float*)d_in[6];
  const float* Wp = (const float*)d_in[7];
  const float* bp = (const float*)d_in[8];

  char* ws = (char*)d_ws;
  // requires ws_size >= 276,824,064 bytes
  unsigned short* xb  = (unsigned short*)(ws);              // 67108864 B; reused as yb
  unsigned short* wb  = (unsigned short*)(ws + 67108864);   // 4 x 2097152 B, frag-packed
  unsigned short* qb  = (unsigned short*)(ws + 75497472);   // 67108864 B
  unsigned short* kTb = (unsigned short*)(ws + 142606336);  // 67108864 B
  unsigned short* vTb = (unsigned short*)(ws + 209715200);  // 67108864 B

  cvt_x<<<2048, 256, 0, stream>>>(x, xb, 33554432 / 4);
  cvt_w<<<2048, 256, 0, stream>>>(Wq, Wk, Wv, Wp, wb);

  gemm_pipe<0><<<6144, 256, 0, stream>>>(xb, wb, bq, bk, bv, qb, kTb, vTb, nullptr);

  attn_kernel<<<512, 256, 0, stream>>>(qb, kTb, vTb, xb /* = yb */);

  gemm_pipe<1><<<2048, 256, 0, stream>>>(xb /* yb */, wb + 3145728, bp, bp, bp,
                                         nullptr, nullptr, nullptr, (float*)d_out);
}

// Round 12
// 462.715 us; speedup vs baseline: 1.2238x; 1.2238x over previous
//
#include <hip/hip_runtime.h>
#include <stdint.h>

// B=8, T=4096, C=1024, NH=64, HD=16. M = B*T = 32768.

typedef __attribute__((ext_vector_type(8))) __bf16 bf16x8;
typedef __attribute__((ext_vector_type(4))) float f32x4;
typedef __attribute__((ext_vector_type(4))) unsigned int u32x4;
typedef __attribute__((ext_vector_type(4))) unsigned short u16x4;

#define AS1 __attribute__((address_space(1)))
#define AS3 __attribute__((address_space(3)))

__device__ __forceinline__ unsigned short f2bf(float f) {
  unsigned int u = __builtin_bit_cast(unsigned int, f);
  u += 0x7FFFu + ((u >> 16) & 1u);
  return (unsigned short)(u >> 16);
}

__device__ __forceinline__ void gl_lds16(const unsigned short* g, unsigned short* l) {
  __builtin_amdgcn_global_load_lds((const AS1 unsigned int*)g, (AS3 unsigned int*)l, 16, 0, 0);
}

// ---------------- fp32 -> bf16 converts ----------------
__global__ __launch_bounds__(256)
void cvt_x(const float* __restrict__ src, unsigned short* __restrict__ dst, int n4) {
  int i = blockIdx.x * blockDim.x + threadIdx.x;
  const int stride = gridDim.x * blockDim.x;
  for (; i < n4; i += stride) {
    f32x4 v = *(const f32x4*)(src + (size_t)i * 4);
    u16x4 o;
    o.x = f2bf(v.x); o.y = f2bf(v.y); o.z = f2bf(v.z); o.w = f2bf(v.w);
    *(u16x4*)(dst + (size_t)i * 4) = o;
  }
}

// Repack all four 1024x1024 weights into MFMA-fragment order (r4-validated):
// per weight, block f = n16*32 + ks32 (1KB each); lane l holds
// W[n16*16 + (l&15)][ks32*32 + (l>>4)*8 .. +8].
__global__ __launch_bounds__(256)
void cvt_w(const float* __restrict__ w0, const float* __restrict__ w1,
           const float* __restrict__ w2, const float* __restrict__ w3,
           unsigned short* __restrict__ dst) {
  const int g = blockIdx.x * 256 + threadIdx.x;   // 0..524287
  const int w = g >> 17;
  const int r = g & 131071;
  const int f = r >> 6;                           // n16*32 + ks32
  const int l = r & 63;
  const int n = (f >> 5) * 16 + (l & 15);
  const int k = (f & 31) * 32 + (l >> 4) * 8;
  const float* ws[4] = {w0, w1, w2, w3};
  const float* src = ws[w] + (size_t)n * 1024 + k;
  f32x4 v0 = *(const f32x4*)src;
  f32x4 v1 = *(const f32x4*)(src + 4);
  u16x4 a, b;
  a.x = f2bf(v0.x); a.y = f2bf(v0.y); a.z = f2bf(v0.z); a.w = f2bf(v0.w);
  b.x = f2bf(v1.x); b.y = f2bf(v1.y); b.z = f2bf(v1.z); b.w = f2bf(v1.w);
  unsigned short* o = dst + (size_t)g * 8;
  *(u16x4*)o = a;
  *(u16x4*)(o + 4) = b;
}

// ---------------- pipelined 128x128-tile bf16 GEMM, B direct from L2 ----------------
// r10 structure EXACTLY (best measured: 477us total, QKV 275us).
// out[m][n] = sum_k A[m][k] * W[n][k] + bias[n]
// KIND 0: fused QKV, N=3072; KIND 1: proj, N=1024 (fp32 out).
template<int KIND>
__global__ __launch_bounds__(256, 3)
void gemm_pipe(const unsigned short* __restrict__ A,
               const unsigned short* __restrict__ Wf,
               const float* __restrict__ b0, const float* __restrict__ b1,
               const float* __restrict__ b2,
               unsigned short* __restrict__ oq, unsigned short* __restrict__ okT,
               unsigned short* __restrict__ ovT, float* __restrict__ of)
{
  __shared__ __align__(16) unsigned short lds[12288];   // 3 bufs x 128x32 bf16

  const int tid  = threadIdx.x;
  const int lane = tid & 63;
  const int wid  = tid >> 6;

  // XCD-aware bijective order: per XCD, (col-group) x (32 A-panels) x (8 cols).
  const int flat  = blockIdx.x;
  const int xcd   = flat & 7;
  const int i     = flat >> 3;
  const int bcg   = i >> 8;
  const int r     = i & 255;
  const int panel = r >> 3;
  const int c     = r & 7;
  const int brow  = (xcd * 32 + panel) * 128;
  const int bcol  = (bcg * 8 + c) * 128;

  // A staging: instr o: row = o*64 + wid*16 + lane/4; dest 16B-slot = lane&3;
  // source slot = (lane&3) ^ ((row>>1)&3)  (XOR swizzle, 2-way conflicts = free)
  const int srow = wid * 16 + (lane >> 2);
  const int scol = ((lane & 3) ^ ((lane >> 3) & 3)) << 3;
  const unsigned short* a_src = A + (size_t)(brow + srow) * 1024 + scol;
  unsigned short* Ldst = lds + wid * 512;

  const int wm = (wid >> 1) * 64;       // wave tile 64x64
  const int wn = (wid & 1) * 64;
  const int fr = lane & 15;
  const int fg = lane >> 4;
  const int aoff = (wm + fr) * 32 + ((fg ^ ((fr >> 1) & 3)) << 3);

  // B fragment pointer: frag block = ((bcol+wn)>>4 + nt)*32 + t, 1KB/block, 16B/lane.
  const unsigned short* wfp = Wf + ((size_t)((bcol + wn) >> 4) * 32) * 512 + lane * 8;

  const f32x4 fz = {0.f, 0.f, 0.f, 0.f};
  f32x4 acc[4][4];
  #pragma unroll
  for (int mt = 0; mt < 4; ++mt)
    #pragma unroll
    for (int nt = 0; nt < 4; ++nt) acc[mt][nt] = fz;

  auto stage = [&](int t, int buf) {
    unsigned short* d = Ldst + buf * 4096;
    gl_lds16(a_src + t * 32, d);
    gl_lds16(a_src + t * 32 + 65536, d + 2048);
  };
  auto loadB = [&](int t, bf16x8 (&dst)[4]) {
    #pragma unroll
    for (int nt = 0; nt < 4; ++nt)
      dst[nt] = __builtin_bit_cast(bf16x8,
        *(const u32x4*)(wfp + (size_t)t * 512 + (size_t)nt * 16384));
  };

  bf16x8 brgA[4], brgB[4];

  // prologue: queue = B0(4), A0(2), A1(2), A2(2); vmcnt(4) -> B0,A0 landed.
  loadB(0, brgA);
  stage(0, 0); stage(1, 1); stage(2, 2);
  asm volatile("s_waitcnt vmcnt(4)" ::: "memory");
  __builtin_amdgcn_sched_barrier(0);
  __builtin_amdgcn_s_barrier();

  auto body = [&](int t, bf16x8 (&bc_)[4], bf16x8 (&bn_)[4]) {
    const unsigned short* Lb = lds + (t % 3) * 4096;
    bf16x8 af[4];
    #pragma unroll
    for (int mt = 0; mt < 4; ++mt)
      af[mt] = __builtin_bit_cast(bf16x8, *(const u32x4*)&Lb[aoff + mt * 512]);
    asm volatile("s_waitcnt lgkmcnt(0)" ::: "memory");   // my reads of this buf done
    __builtin_amdgcn_sched_barrier(0);
    __builtin_amdgcn_s_barrier();                        // all waves' reads done
    if (t + 3 < 32) stage(t + 3, t % 3);                 // refill just-freed buffer
    if (t + 1 < 32) loadB(t + 1, bn_);                   // next B frags -> regs
    // steady: allow A(t+3)(2)+B(t+1)(4)=6 outstanding; forces B(t),A(t+2) landed.
    if (t <= 28)      asm volatile("s_waitcnt vmcnt(6)" ::: "memory");
    else if (t <= 30) asm volatile("s_waitcnt vmcnt(4)" ::: "memory");
    else              asm volatile("s_waitcnt vmcnt(0)" ::: "memory");
    __builtin_amdgcn_sched_barrier(0);
    __builtin_amdgcn_s_setprio(1);
    #pragma unroll
    for (int mt = 0; mt < 4; ++mt)
      #pragma unroll
      for (int nt = 0; nt < 4; ++nt)
        acc[mt][nt] = __builtin_amdgcn_mfma_f32_16x16x32_bf16(af[mt], bc_[nt], acc[mt][nt], 0, 0, 0);
    __builtin_amdgcn_s_setprio(0);
    // (trailing barrier removed — r10 audit)
  };

  for (int t = 0; t < 32; t += 2) {   // static parity -> brgA/brgB never runtime-indexed
    body(t,     brgA, brgB);
    body(t + 1, brgB, brgA);
  }

  // ---------------- epilogue ----------------
  const int sec = (KIND == 0) ? (bcol >> 10) : 0;
  const float* bias = (KIND == 1) ? b0 : (sec == 0 ? b0 : (sec == 1 ? b1 : b2));

  #pragma unroll
  for (int nt = 0; nt < 4; ++nt) {
    const int n_glob = bcol + wn + nt * 16 + fr;
    const int nn = (KIND == 0) ? (n_glob & 1023) : n_glob;
    const float bv = bias[nn];
    #pragma unroll
    for (int mt = 0; mt < 4; ++mt) {
      const int m0 = brow + wm + mt * 16 + fg * 4;
      float vals[4];
      #pragma unroll
      for (int r2 = 0; r2 < 4; ++r2) vals[r2] = acc[mt][nt][r2] + bv;

      if (KIND == 0 && sec <= 1) {
        // softmax over the 16 columns (one head's HD), per row.
        // No max-subtraction: |q| <= ~6 -> exp safe in fp32 (validated r9/r10).
        #pragma unroll
        for (int r2 = 0; r2 < 4; ++r2) {
          float e = __expf(vals[r2]);
          float sm = e;
          #pragma unroll
          for (int s = 1; s < 16; s <<= 1) sm += __shfl_xor(sm, s, 64);
          vals[r2] = e * __builtin_amdgcn_rcpf(sm);
        }
      }

      if (KIND == 1) {
        #pragma unroll
        for (int r2 = 0; r2 < 4; ++r2)
          of[(size_t)(m0 + r2) * 1024 + n_glob] = vals[r2];
      } else if (sec == 0) {
        #pragma unroll
        for (int r2 = 0; r2 < 4; ++r2)
          oq[(size_t)(m0 + r2) * 1024 + nn] = f2bf(vals[r2]);
      } else {
        // transposed per head: dst[((b*64+h)*16+d)*4096 + t]
        unsigned short* o = (sec == 1) ? okT : ovT;
        const int bb = m0 >> 12;
        const int t0 = m0 & 4095;
        const int hh = nn >> 4;
        const int dd = nn & 15;
        u16x4 pk;
        pk.x = f2bf(vals[0]); pk.y = f2bf(vals[1]);
        pk.z = f2bf(vals[2]); pk.w = f2bf(vals[3]);
        *(u16x4*)&o[(((size_t)bb * 64 + hh) * 16 + dd) * 4096 + t0] = pk;
      }
    }
  }
}

// ---------------- per-head-PAIR linear-attention middle (r12) ----------------
// One block = heads (2hp, 2hp+1) = 32 contiguous C-columns = 64B span.
// Phase 2: every lane loads a full 16B of q covering the pair (all 64 lanes
// active, 64B lines fully consumed); 4 zero-padded MFMAs per 16 rows give
// y and denominator for both heads; writes cover full 64B lines.
__global__ __launch_bounds__(256)
void attn_kernel(const unsigned short* __restrict__ qb,
                 const unsigned short* __restrict__ kT,
                 const unsigned short* __restrict__ vT,
                 unsigned short* __restrict__ yb)
{
  const int pair = blockIdx.x;           // b*32 + hp
  const int b    = pair >> 5;
  const int hp   = pair & 31;
  const int tid  = threadIdx.x;
  const int lane = tid & 63;
  const int wid  = tid >> 6;
  const int fr   = lane & 15;
  const int fg   = lane >> 4;

  const unsigned short* kT0 = kT + ((size_t)(b * 64 + hp * 2) * 16) * 4096;
  const unsigned short* vT0 = vT + ((size_t)(b * 64 + hp * 2) * 16) * 4096;
  const unsigned short* kT1 = kT0 + 16 * 4096;
  const unsigned short* vT1 = vT0 + 16 * 4096;

  const u32x4 uz = {0u, 0u, 0u, 0u};
  const f32x4 fz = {0.f, 0.f, 0.f, 0.f};
  const u32x4 uo = {0x3F803F80u, 0x3F803F80u, 0x3F803F80u, 0x3F803F80u};
  const bf16x8 ones = __builtin_bit_cast(bf16x8, uo);

  f32x4 cctx0 = fz, ckc0 = fz, cctx1 = fz, ckc1 = fz;
  #pragma unroll 2
  for (int t0 = wid * 1024; t0 < (wid + 1) * 1024; t0 += 32) {
    const size_t off = (size_t)fr * 4096 + t0 + fg * 8;
    bf16x8 ak0 = __builtin_bit_cast(bf16x8, *(const u32x4*)&kT0[off]);
    bf16x8 bv0 = __builtin_bit_cast(bf16x8, *(const u32x4*)&vT0[off]);
    bf16x8 ak1 = __builtin_bit_cast(bf16x8, *(const u32x4*)&kT1[off]);
    bf16x8 bv1 = __builtin_bit_cast(bf16x8, *(const u32x4*)&vT1[off]);
    cctx0 = __builtin_amdgcn_mfma_f32_16x16x32_bf16(ak0, bv0, cctx0, 0, 0, 0);
    ckc0  = __builtin_amdgcn_mfma_f32_16x16x32_bf16(ak0, ones, ckc0, 0, 0, 0);
    cctx1 = __builtin_amdgcn_mfma_f32_16x16x32_bf16(ak1, bv1, cctx1, 0, 0, 0);
    ckc1  = __builtin_amdgcn_mfma_f32_16x16x32_bf16(ak1, ones, ckc1, 0, 0, 0);
  }

  __shared__ float red[4][2][16][16];
  __shared__ float kcr[4][2][16];
  __shared__ float ctxf[2][16][16];
  __shared__ float kcf[2][16];

  #pragma unroll
  for (int r = 0; r < 4; ++r) {
    red[wid][0][fg * 4 + r][fr] = cctx0[r];
    red[wid][1][fg * 4 + r][fr] = cctx1[r];
  }
  if (fr == 0) {
    #pragma unroll
    for (int r = 0; r < 4; ++r) {
      kcr[wid][0][fg * 4 + r] = ckc0[r];
      kcr[wid][1][fg * 4 + r] = ckc1[r];
    }
  }
  __syncthreads();
  {
    const int h = tid >> 8;  // 0 (256 threads) — handle both heads by loop
    (void)h;
    const int d = (tid >> 4) & 15, e = tid & 15;
    #pragma unroll
    for (int hh = 0; hh < 2; ++hh)
      ctxf[hh][d][e] = red[0][hh][d][e] + red[1][hh][d][e] + red[2][hh][d][e] + red[3][hh][d][e];
    if (tid < 32) {
      const int hh = tid >> 4, dd = tid & 15;
      kcf[hh][dd] = kcr[0][hh][dd] + kcr[1][hh][dd] + kcr[2][hh][dd] + kcr[3][hh][dd];
    }
  }
  __syncthreads();

  // Block-diagonal B fragments: k index = fg*8+j spans head0 (k<16) / head1 (k>=16).
  bf16x8 bctx0 = __builtin_bit_cast(bf16x8, uz);
  bf16x8 bctx1 = __builtin_bit_cast(bf16x8, uz);
  bf16x8 bkc0  = __builtin_bit_cast(bf16x8, uz);
  bf16x8 bkc1  = __builtin_bit_cast(bf16x8, uz);
  if (fg < 2) {
    #pragma unroll
    for (int j = 0; j < 8; ++j) {
      const int d = fg * 8 + j;
      bctx0[j] = (__bf16)ctxf[0][d][fr];
      bkc0[j]  = (__bf16)kcf[0][d];
    }
  } else {
    #pragma unroll
    for (int j = 0; j < 8; ++j) {
      const int d = (fg - 2) * 8 + j;
      bctx1[j] = (__bf16)ctxf[1][d][fr];
      bkc1[j]  = (__bf16)kcf[1][d];
    }
  }

  const size_t cbase = (size_t)b * 4096 * 1024 + (size_t)hp * 32;

  for (int step = 0; step < 64; ++step) {
    const int t0 = step * 64 + wid * 16;
    // full 16B load per lane: cols hp*32 + fg*8 .. +8 (covers both heads)
    bf16x8 af = __builtin_bit_cast(bf16x8,
        *(const u32x4*)&qb[cbase + (size_t)(t0 + fr) * 1024 + fg * 8]);
    f32x4 cy0 = __builtin_amdgcn_mfma_f32_16x16x32_bf16(af, bctx0, fz, 0, 0, 0);
    f32x4 cy1 = __builtin_amdgcn_mfma_f32_16x16x32_bf16(af, bctx1, fz, 0, 0, 0);
    f32x4 cd0 = __builtin_amdgcn_mfma_f32_16x16x32_bf16(af, bkc0,  fz, 0, 0, 0);
    f32x4 cd1 = __builtin_amdgcn_mfma_f32_16x16x32_bf16(af, bkc1,  fz, 0, 0, 0);
    #pragma unroll
    for (int r = 0; r < 4; ++r) {
      const int t = t0 + fg * 4 + r;
      const size_t o = cbase + (size_t)t * 1024;
      yb[o + fr]      = f2bf(cy0[r] * __builtin_amdgcn_rcpf(cd0[r]));
      yb[o + 16 + fr] = f2bf(cy1[r] * __builtin_amdgcn_rcpf(cd1[r]));
    }
  }
}

// ---------------- launch ----------------
extern "C" void kernel_launch(void* const* d_in, const int* in_sizes, int n_in,
                              void* d_out, int out_size, void* d_ws, size_t ws_size,
                              hipStream_t stream)
{
  (void)in_sizes; (void)n_in; (void)out_size; (void)ws_size;
  const float* x  = (const float*)d_in[0];
  const float* Wq = (const float*)d_in[1];
  const float* bq = (const float*)d_in[2];
  const float* Wk = (const float*)d_in[3];
  const float* bk = (const float*)d_in[4];
  const float* Wv = (const float*)d_in[5];
  const float* bv = (const float*)d_in[6];
  const float* Wp = (const float*)d_in[7];
  const float* bp = (const float*)d_in[8];

  char* ws = (char*)d_ws;
  // requires ws_size >= 276,824,064 bytes
  unsigned short* xb  = (unsigned short*)(ws);              // 67108864 B; reused as yb
  unsigned short* wb  = (unsigned short*)(ws + 67108864);   // 4 x 2097152 B, frag-packed
  unsigned short* qb  = (unsigned short*)(ws + 75497472);   // 67108864 B
  unsigned short* kTb = (unsigned short*)(ws + 142606336);  // 67108864 B
  unsigned short* vTb = (unsigned short*)(ws + 209715200);  // 67108864 B

  cvt_x<<<2048, 256, 0, stream>>>(x, xb, 33554432 / 4);
  cvt_w<<<2048, 256, 0, stream>>>(Wq, Wk, Wv, Wp, wb);

  gemm_pipe<0><<<6144, 256, 0, stream>>>(xb, wb, bq, bk, bv, qb, kTb, vTb, nullptr);

  attn_kernel<<<256, 256, 0, stream>>>(qb, kTb, vTb, xb /* = yb */);

  gemm_pipe<1><<<2048, 256, 0, stream>>>(xb /* yb */, wb + 3145728, bp, bp, bp,
                                         nullptr, nullptr, nullptr, (float*)d_out);
}

// Round 13
// 453.470 us; speedup vs baseline: 1.2487x; 1.0204x over previous
//
#include <hip/hip_runtime.h>
#include <stdint.h>

// B=8, T=4096, C=1024, NH=64, HD=16. M = B*T = 32768.

typedef __attribute__((ext_vector_type(8))) __bf16 bf16x8;
typedef __attribute__((ext_vector_type(4))) float f32x4;
typedef __attribute__((ext_vector_type(4))) unsigned int u32x4;
typedef __attribute__((ext_vector_type(4))) unsigned short u16x4;

#define AS1 __attribute__((address_space(1)))
#define AS3 __attribute__((address_space(3)))

__device__ __forceinline__ unsigned short f2bf(float f) {
  unsigned int u = __builtin_bit_cast(unsigned int, f);
  u += 0x7FFFu + ((u >> 16) & 1u);
  return (unsigned short)(u >> 16);
}

__device__ __forceinline__ void gl_lds16(const unsigned short* g, unsigned short* l) {
  __builtin_amdgcn_global_load_lds((const AS1 unsigned int*)g, (AS3 unsigned int*)l, 16, 0, 0);
}

// ---------------- fp32 -> bf16 converts ----------------
__global__ __launch_bounds__(256)
void cvt_x(const float* __restrict__ src, unsigned short* __restrict__ dst, int n4) {
  int i = blockIdx.x * blockDim.x + threadIdx.x;
  const int stride = gridDim.x * blockDim.x;
  for (; i < n4; i += stride) {
    f32x4 v = *(const f32x4*)(src + (size_t)i * 4);
    u16x4 o;
    o.x = f2bf(v.x); o.y = f2bf(v.y); o.z = f2bf(v.z); o.w = f2bf(v.w);
    *(u16x4*)(dst + (size_t)i * 4) = o;
  }
}

// Repack all four 1024x1024 weights into MFMA-fragment order (r4-validated):
// per weight, block f = n16*32 + ks32 (1KB each); lane l holds
// W[n16*16 + (l&15)][ks32*32 + (l>>4)*8 .. +8].
__global__ __launch_bounds__(256)
void cvt_w(const float* __restrict__ w0, const float* __restrict__ w1,
           const float* __restrict__ w2, const float* __restrict__ w3,
           unsigned short* __restrict__ dst) {
  const int g = blockIdx.x * 256 + threadIdx.x;   // 0..524287
  const int w = g >> 17;
  const int r = g & 131071;
  const int f = r >> 6;                           // n16*32 + ks32
  const int l = r & 63;
  const int n = (f >> 5) * 16 + (l & 15);
  const int k = (f & 31) * 32 + (l >> 4) * 8;
  const float* ws[4] = {w0, w1, w2, w3};
  const float* src = ws[w] + (size_t)n * 1024 + k;
  f32x4 v0 = *(const f32x4*)src;
  f32x4 v1 = *(const f32x4*)(src + 4);
  u16x4 a, b;
  a.x = f2bf(v0.x); a.y = f2bf(v0.y); a.z = f2bf(v0.z); a.w = f2bf(v0.w);
  b.x = f2bf(v1.x); b.y = f2bf(v1.y); b.z = f2bf(v1.z); b.w = f2bf(v1.w);
  unsigned short* o = dst + (size_t)g * 8;
  *(u16x4*)o = a;
  *(u16x4*)(o + 4) = b;
}

// ---------------- BK=64-body pipelined 128x128 bf16 GEMM (r13) ----------------
// r10 hazard discipline, supertiles of 64 k: HALF the barriers/lgkm convoys.
// A: ring of 3 x 16KB superbuffers (2 x 32-k halves, r10 layout each).
// B: frag-packed, regs. bEven=B(2T) (loaded mid body T-1), bOdd=B(2T+1) (top).
//
// Body T: 8 ds_read (slot T%3) ; lgkm ; issue stage(T+2)->slot (T-1)%3 +
//   loadB(2T+1) ; vmcnt#1 ; BARRIER ; 32 MFMA half0 ; loadB(2T+2) ; vmcnt#2 ;
//   32 MFMA half1.
// In-order vmcnt ledger (4 loads per stage, 4 per loadB):
//  #1, T<=13: outstanding {stage(T+1),B(2T),B(2T+1),stage(T+2)}=16 -> vmcnt(8)
//     completes stage(T+1) [publishing!] and B(2T) [half0 operand].
//  #2, T<=13: {B(2T+1),stage(T+2),B(2T+2)}=12 -> vmcnt(8) completes B(2T+1).
//  T=14: #1 {stage(15),B(28),B(29)}=12 -> vmcnt(4); #2 {B(29),B(30)}=8 -> vmcnt(4).
//  T=15: #1 {B(30),B(31)}=8 -> vmcnt(4); #2 {B(31)}=4 -> vmcnt(0); no barrier.
// RAW publish: stage(T+1) completed (in-order) before barrier(T); readers'
//   ds_reads of slot (T+1)%3 happen at body T+1, after they passed barrier(T).
// WAR: stage(T+2) targets slot (T-1)%3; all waves' reads of it retired
//   (lgkm) before barrier(T-1), which the issuing wave passed first.
// out[m][n] = sum_k A[m][k] * W[n][k] + bias[n]
// KIND 0: fused QKV, N=3072; KIND 1: proj, N=1024 (fp32 out).
template<int KIND>
__global__ __launch_bounds__(256, 3)
void gemm_pipe(const unsigned short* __restrict__ A,
               const unsigned short* __restrict__ Wf,
               const float* __restrict__ b0, const float* __restrict__ b1,
               const float* __restrict__ b2,
               unsigned short* __restrict__ oq, unsigned short* __restrict__ okT,
               unsigned short* __restrict__ ovT, float* __restrict__ of)
{
  __shared__ __align__(16) unsigned short lds[24576];   // 3 superbufs x 128x64 bf16

  const int tid  = threadIdx.x;
  const int lane = tid & 63;
  const int wid  = tid >> 6;

  // XCD-aware bijective order: per XCD, (col-group) x (32 A-panels) x (8 cols).
  const int flat  = blockIdx.x;
  const int xcd   = flat & 7;
  const int i     = flat >> 3;
  const int bcg   = i >> 8;
  const int r     = i & 255;
  const int panel = r >> 3;
  const int c     = r & 7;
  const int brow  = (xcd * 32 + panel) * 128;
  const int bcol  = (bcg * 8 + c) * 128;

  // A staging (per 32-k half, r10 mapping): instr o: row = o*64+wid*16+lane/4;
  // dest 16B-slot = lane&3; src slot = (lane&3)^((lane>>3)&3) (XOR swizzle).
  const int srow = wid * 16 + (lane >> 2);
  const int scol = ((lane & 3) ^ ((lane >> 3) & 3)) << 3;
  const unsigned short* a_src = A + (size_t)(brow + srow) * 1024 + scol;
  unsigned short* Ldst = lds + wid * 512;

  const int wm = (wid >> 1) * 64;       // wave tile 64x64
  const int wn = (wid & 1) * 64;
  const int fr = lane & 15;
  const int fg = lane >> 4;
  const int aoff = (wm + fr) * 32 + ((fg ^ ((fr >> 1) & 3)) << 3);

  // B fragment pointer: frag block = ((bcol+wn)>>4 + nt)*32 + k32, 1KB/block.
  const unsigned short* wfp = Wf + ((size_t)((bcol + wn) >> 4) * 32) * 512 + lane * 8;

  const f32x4 fz = {0.f, 0.f, 0.f, 0.f};
  f32x4 acc[4][4];
  #pragma unroll
  for (int mt = 0; mt < 4; ++mt)
    #pragma unroll
    for (int nt = 0; nt < 4; ++nt) acc[mt][nt] = fz;

  // stage supertile T into superbuffer sb (4 gl_lds: 2 halves x 2 instrs)
  auto stage = [&](int T, int sb) {
    unsigned short* d = Ldst + sb * 8192;
    const unsigned short* g = a_src + T * 64;
    gl_lds16(g,              d);
    gl_lds16(g + 65536,      d + 2048);
    gl_lds16(g + 32,         d + 4096);
    gl_lds16(g + 65536 + 32, d + 6144);
  };
  auto loadB = [&](int k32, bf16x8 (&dst)[4]) {
    #pragma unroll
    for (int nt = 0; nt < 4; ++nt)
      dst[nt] = __builtin_bit_cast(bf16x8,
        *(const u32x4*)(wfp + (size_t)k32 * 512 + (size_t)nt * 16384));
  };

  bf16x8 bEven[4], bOdd[4];

  // prologue: stage(0)->sb0, stage(1)->sb1 (8 loads), loadB(0) (4 loads).
  // vmcnt(8) completes stage(0); barrier publishes it.
  stage(0, 0); stage(1, 1);
  loadB(0, bEven);
  asm volatile("s_waitcnt vmcnt(8)" ::: "memory");
  __builtin_amdgcn_sched_barrier(0);
  __builtin_amdgcn_s_barrier();

  for (int T = 0; T < 16; ++T) {
    const unsigned short* Lb = lds + (T % 3) * 8192;
    bf16x8 af[8];
    #pragma unroll
    for (int mt = 0; mt < 4; ++mt) {
      af[mt]     = __builtin_bit_cast(bf16x8, *(const u32x4*)&Lb[aoff + mt * 512]);
      af[4 + mt] = __builtin_bit_cast(bf16x8, *(const u32x4*)&Lb[4096 + aoff + mt * 512]);
    }
    asm volatile("s_waitcnt lgkmcnt(0)" ::: "memory");   // af in regs
    __builtin_amdgcn_sched_barrier(0);
    if (T + 2 < 16) stage(T + 2, (T + 2) % 3);
    loadB(2 * T + 1, bOdd);
    if (T <= 13)      asm volatile("s_waitcnt vmcnt(8)" ::: "memory");
    else              asm volatile("s_waitcnt vmcnt(4)" ::: "memory");
    __builtin_amdgcn_sched_barrier(0);
    if (T < 15) __builtin_amdgcn_s_barrier();            // publishes stage(T+1)

    __builtin_amdgcn_s_setprio(1);
    #pragma unroll
    for (int mt = 0; mt < 4; ++mt)
      #pragma unroll
      for (int nt = 0; nt < 4; ++nt)
        acc[mt][nt] = __builtin_amdgcn_mfma_f32_16x16x32_bf16(af[mt], bEven[nt], acc[mt][nt], 0, 0, 0);
    __builtin_amdgcn_s_setprio(0);

    if (T <= 14) loadB(2 * T + 2, bEven);
    if (T <= 13)      asm volatile("s_waitcnt vmcnt(8)" ::: "memory");
    else if (T == 14) asm volatile("s_waitcnt vmcnt(4)" ::: "memory");
    else              asm volatile("s_waitcnt vmcnt(0)" ::: "memory");
    __builtin_amdgcn_sched_barrier(0);

    __builtin_amdgcn_s_setprio(1);
    #pragma unroll
    for (int mt = 0; mt < 4; ++mt)
      #pragma unroll
      for (int nt = 0; nt < 4; ++nt)
        acc[mt][nt] = __builtin_amdgcn_mfma_f32_16x16x32_bf16(af[4 + mt], bOdd[nt], acc[mt][nt], 0, 0, 0);
    __builtin_amdgcn_s_setprio(0);
  }

  // ---------------- epilogue ----------------
  const int sec = (KIND == 0) ? (bcol >> 10) : 0;
  const float* bias = (KIND == 1) ? b0 : (sec == 0 ? b0 : (sec == 1 ? b1 : b2));

  #pragma unroll
  for (int nt = 0; nt < 4; ++nt) {
    const int n_glob = bcol + wn + nt * 16 + fr;
    const int nn = (KIND == 0) ? (n_glob & 1023) : n_glob;
    const float bv = bias[nn];
    #pragma unroll
    for (int mt = 0; mt < 4; ++mt) {
      const int m0 = brow + wm + mt * 16 + fg * 4;
      float vals[4];
      #pragma unroll
      for (int r2 = 0; r2 < 4; ++r2) vals[r2] = acc[mt][nt][r2] + bv;

      if (KIND == 0 && sec <= 1) {
        // softmax over the 16 columns (one head's HD), per row.
        // No max-subtraction: |q| <= ~6 -> exp safe in fp32 (validated r9/r10).
        #pragma unroll
        for (int r2 = 0; r2 < 4; ++r2) {
          float e = __expf(vals[r2]);
          float sm = e;
          #pragma unroll
          for (int s = 1; s < 16; s <<= 1) sm += __shfl_xor(sm, s, 64);
          vals[r2] = e * __builtin_amdgcn_rcpf(sm);
        }
      }

      if (KIND == 1) {
        #pragma unroll
        for (int r2 = 0; r2 < 4; ++r2)
          of[(size_t)(m0 + r2) * 1024 + n_glob] = vals[r2];
      } else if (sec == 0) {
        #pragma unroll
        for (int r2 = 0; r2 < 4; ++r2)
          oq[(size_t)(m0 + r2) * 1024 + nn] = f2bf(vals[r2]);
      } else {
        // transposed per head: dst[((b*64+h)*16+d)*4096 + t]
        unsigned short* o = (sec == 1) ? okT : ovT;
        const int bb = m0 >> 12;
        const int t0 = m0 & 4095;
        const int hh = nn >> 4;
        const int dd = nn & 15;
        u16x4 pk;
        pk.x = f2bf(vals[0]); pk.y = f2bf(vals[1]);
        pk.z = f2bf(vals[2]); pk.w = f2bf(vals[3]);
        *(u16x4*)&o[(((size_t)bb * 64 + hh) * 16 + dd) * 4096 + t0] = pk;
      }
    }
  }
}

// ---------------- per-head-PAIR linear-attention middle (r12, kept) ----------------
__global__ __launch_bounds__(256)
void attn_kernel(const unsigned short* __restrict__ qb,
                 const unsigned short* __restrict__ kT,
                 const unsigned short* __restrict__ vT,
                 unsigned short* __restrict__ yb)
{
  const int pair = blockIdx.x;           // b*32 + hp
  const int b    = pair >> 5;
  const int hp   = pair & 31;
  const int tid  = threadIdx.x;
  const int lane = tid & 63;
  const int wid  = tid >> 6;
  const int fr   = lane & 15;
  const int fg   = lane >> 4;

  const unsigned short* kT0 = kT + ((size_t)(b * 64 + hp * 2) * 16) * 4096;
  const unsigned short* vT0 = vT + ((size_t)(b * 64 + hp * 2) * 16) * 4096;
  const unsigned short* kT1 = kT0 + 16 * 4096;
  const unsigned short* vT1 = vT0 + 16 * 4096;

  const u32x4 uz = {0u, 0u, 0u, 0u};
  const f32x4 fz = {0.f, 0.f, 0.f, 0.f};
  const u32x4 uo = {0x3F803F80u, 0x3F803F80u, 0x3F803F80u, 0x3F803F80u};
  const bf16x8 ones = __builtin_bit_cast(bf16x8, uo);

  f32x4 cctx0 = fz, ckc0 = fz, cctx1 = fz, ckc1 = fz;
  #pragma unroll 2
  for (int t0 = wid * 1024; t0 < (wid + 1) * 1024; t0 += 32) {
    const size_t off = (size_t)fr * 4096 + t0 + fg * 8;
    bf16x8 ak0 = __builtin_bit_cast(bf16x8, *(const u32x4*)&kT0[off]);
    bf16x8 bv0 = __builtin_bit_cast(bf16x8, *(const u32x4*)&vT0[off]);
    bf16x8 ak1 = __builtin_bit_cast(bf16x8, *(const u32x4*)&kT1[off]);
    bf16x8 bv1 = __builtin_bit_cast(bf16x8, *(const u32x4*)&vT1[off]);
    cctx0 = __builtin_amdgcn_mfma_f32_16x16x32_bf16(ak0, bv0, cctx0, 0, 0, 0);
    ckc0  = __builtin_amdgcn_mfma_f32_16x16x32_bf16(ak0, ones, ckc0, 0, 0, 0);
    cctx1 = __builtin_amdgcn_mfma_f32_16x16x32_bf16(ak1, bv1, cctx1, 0, 0, 0);
    ckc1  = __builtin_amdgcn_mfma_f32_16x16x32_bf16(ak1, ones, ckc1, 0, 0, 0);
  }

  __shared__ float red[4][2][16][16];
  __shared__ float kcr[4][2][16];
  __shared__ float ctxf[2][16][16];
  __shared__ float kcf[2][16];

  #pragma unroll
  for (int r = 0; r < 4; ++r) {
    red[wid][0][fg * 4 + r][fr] = cctx0[r];
    red[wid][1][fg * 4 + r][fr] = cctx1[r];
  }
  if (fr == 0) {
    #pragma unroll
    for (int r = 0; r < 4; ++r) {
      kcr[wid][0][fg * 4 + r] = ckc0[r];
      kcr[wid][1][fg * 4 + r] = ckc1[r];
    }
  }
  __syncthreads();
  {
    const int d = (tid >> 4) & 15, e = tid & 15;
    #pragma unroll
    for (int hh = 0; hh < 2; ++hh)
      ctxf[hh][d][e] = red[0][hh][d][e] + red[1][hh][d][e] + red[2][hh][d][e] + red[3][hh][d][e];
    if (tid < 32) {
      const int hh = tid >> 4, dd = tid & 15;
      kcf[hh][dd] = kcr[0][hh][dd] + kcr[1][hh][dd] + kcr[2][hh][dd] + kcr[3][hh][dd];
    }
  }
  __syncthreads();

  // Block-diagonal B fragments: k index = fg*8+j spans head0 (k<16) / head1 (k>=16).
  bf16x8 bctx0 = __builtin_bit_cast(bf16x8, uz);
  bf16x8 bctx1 = __builtin_bit_cast(bf16x8, uz);
  bf16x8 bkc0  = __builtin_bit_cast(bf16x8, uz);
  bf16x8 bkc1  = __builtin_bit_cast(bf16x8, uz);
  if (fg < 2) {
    #pragma unroll
    for (int j = 0; j < 8; ++j) {
      const int d = fg * 8 + j;
      bctx0[j] = (__bf16)ctxf[0][d][fr];
      bkc0[j]  = (__bf16)kcf[0][d];
    }
  } else {
    #pragma unroll
    for (int j = 0; j < 8; ++j) {
      const int d = (fg - 2) * 8 + j;
      bctx1[j] = (__bf16)ctxf[1][d][fr];
      bkc1[j]  = (__bf16)kcf[1][d];
    }
  }

  const size_t cbase = (size_t)b * 4096 * 1024 + (size_t)hp * 32;

  for (int step = 0; step < 64; ++step) {
    const int t0 = step * 64 + wid * 16;
    bf16x8 af = __builtin_bit_cast(bf16x8,
        *(const u32x4*)&qb[cbase + (size_t)(t0 + fr) * 1024 + fg * 8]);
    f32x4 cy0 = __builtin_amdgcn_mfma_f32_16x16x32_bf16(af, bctx0, fz, 0, 0, 0);
    f32x4 cy1 = __builtin_amdgcn_mfma_f32_16x16x32_bf16(af, bctx1, fz, 0, 0, 0);
    f32x4 cd0 = __builtin_amdgcn_mfma_f32_16x16x32_bf16(af, bkc0,  fz, 0, 0, 0);
    f32x4 cd1 = __builtin_amdgcn_mfma_f32_16x16x32_bf16(af, bkc1,  fz, 0, 0, 0);
    #pragma unroll
    for (int r = 0; r < 4; ++r) {
      const int t = t0 + fg * 4 + r;
      const size_t o = cbase + (size_t)t * 1024;
      yb[o + fr]      = f2bf(cy0[r] * __builtin_amdgcn_rcpf(cd0[r]));
      yb[o + 16 + fr] = f2bf(cy1[r] * __builtin_amdgcn_rcpf(cd1[r]));
    }
  }
}

// ---------------- launch ----------------
extern "C" void kernel_launch(void* const* d_in, const int* in_sizes, int n_in,
                              void* d_out, int out_size, void* d_ws, size_t ws_size,
                              hipStream_t stream)
{
  (void)in_sizes; (void)n_in; (void)out_size; (void)ws_size;
  const float* x  = (const float*)d_in[0];
  const float* Wq = (const float*)d_in[1];
  const float* bq = (const float*)d_in[2];
  const float* Wk = (const float*)d_in[3];
  const float* bk = (const float*)d_in[4];
  const float* Wv = (const float*)d_in[5];
  const float* bv = (const float*)d_in[6];
  const float* Wp = (const float*)d_in[7];
  const float* bp = (const float*)d_in[8];

  char* ws = (char*)d_ws;
  // requires ws_size >= 276,824,064 bytes
  unsigned short* xb  = (unsigned short*)(ws);              // 67108864 B; reused as yb
  unsigned short* wb  = (unsigned short*)(ws + 67108864);   // 4 x 2097152 B, frag-packed
  unsigned short* qb  = (unsigned short*)(ws + 75497472);   // 67108864 B
  unsigned short* kTb = (unsigned short*)(ws + 142606336);  // 67108864 B
  unsigned short* vTb = (unsigned short*)(ws + 209715200);  // 67108864 B

  cvt_x<<<2048, 256, 0, stream>>>(x, xb, 33554432 / 4);
  cvt_w<<<2048, 256, 0, stream>>>(Wq, Wk, Wv, Wp, wb);

  gemm_pipe<0><<<6144, 256, 0, stream>>>(xb, wb, bq, bk, bv, qb, kTb, vTb, nullptr);

  attn_kernel<<<256, 256, 0, stream>>>(qb, kTb, vTb, xb /* = yb */);

  gemm_pipe<1><<<2048, 256, 0, stream>>>(xb /* yb */, wb + 3145728, bp, bp, bp,
                                         nullptr, nullptr, nullptr, (float*)d_out);
}

// Round 14
// 451.452 us; speedup vs baseline: 1.2543x; 1.0045x over previous
//
#include <hip/hip_runtime.h>
#include <stdint.h>

// B=8, T=4096, C=1024, NH=64, HD=16. M = B*T = 32768.

typedef __attribute__((ext_vector_type(8))) __bf16 bf16x8;
typedef __attribute__((ext_vector_type(4))) float f32x4;
typedef __attribute__((ext_vector_type(4))) unsigned int u32x4;
typedef __attribute__((ext_vector_type(4))) unsigned short u16x4;

#define AS1 __attribute__((address_space(1)))
#define AS3 __attribute__((address_space(3)))

__device__ __forceinline__ unsigned short f2bf(float f) {
  unsigned int u = __builtin_bit_cast(unsigned int, f);
  u += 0x7FFFu + ((u >> 16) & 1u);
  return (unsigned short)(u >> 16);
}

__device__ __forceinline__ void gl_lds16(const unsigned short* g, unsigned short* l) {
  __builtin_amdgcn_global_load_lds((const AS1 unsigned int*)g, (AS3 unsigned int*)l, 16, 0, 0);
}

// ---------------- merged fp32 -> bf16 convert (x + 4 weights, one launch) ----------------
// blocks 0..2047: x (8388608 float4, 16 iters/thread).
// blocks 2048..4095: weights, frag-packed repack (r4-validated layout):
//   per weight, block f = n16*32 + ks32 (1KB each); lane l holds
//   W[n16*16 + (l&15)][ks32*32 + (l>>4)*8 .. +8].
__global__ __launch_bounds__(256)
void cvt_all(const float* __restrict__ x,
             const float* __restrict__ w0, const float* __restrict__ w1,
             const float* __restrict__ w2, const float* __restrict__ w3,
             unsigned short* __restrict__ xb, unsigned short* __restrict__ wb) {
  const int blk = blockIdx.x;
  if (blk < 2048) {
    int i = blk * 256 + threadIdx.x;
    #pragma unroll 4
    for (; i < 8388608; i += 524288) {
      f32x4 v = *(const f32x4*)(x + (size_t)i * 4);
      u16x4 o;
      o.x = f2bf(v.x); o.y = f2bf(v.y); o.z = f2bf(v.z); o.w = f2bf(v.w);
      *(u16x4*)(xb + (size_t)i * 4) = o;
    }
  } else {
    const int g = (blk - 2048) * 256 + threadIdx.x;   // 0..524287
    const int w = g >> 17;
    const int r = g & 131071;
    const int f = r >> 6;                             // n16*32 + ks32
    const int l = r & 63;
    const int n = (f >> 5) * 16 + (l & 15);
    const int k = (f & 31) * 32 + (l >> 4) * 8;
    const float* ws[4] = {w0, w1, w2, w3};
    const float* src = ws[w] + (size_t)n * 1024 + k;
    f32x4 v0 = *(const f32x4*)src;
    f32x4 v1 = *(const f32x4*)(src + 4);
    u16x4 a, b;
    a.x = f2bf(v0.x); a.y = f2bf(v0.y); a.z = f2bf(v0.z); a.w = f2bf(v0.w);
    b.x = f2bf(v1.x); b.y = f2bf(v1.y); b.z = f2bf(v1.z); b.w = f2bf(v1.w);
    unsigned short* o = wb + (size_t)g * 8;
    *(u16x4*)o = a;
    *(u16x4*)(o + 4) = b;
  }
}

// ---------------- BK=64-body GEMM with register-pipelined A-fragments (r14) ----------------
// r13 supertile structure; ds_reads moved OFF the critical path:
//   af0 (half0 of supertile T) prefetched during body T-1 (after its barrier);
//   af1 (half1 of supertile T) read at body-T top, consumed after 16 MFMAs.
// The explicit lgkmcnt(0) convoy is GONE.
//
// Body T:  1. loadB(2T+1)->bOdd
//          2. 4 ds_read af1 <- slot T%3 half1        (RAW: stage(T) completed
//             at body T-1 vmcnt#1, published by body T-1 barrier)
//          3. vmcnt(4)  [completes stage(T+1), B(2T); leaves B(2T+1)]
//          4. BARRIER   [publishes stage(T+1)]                  (T<15)
//          5. stage(T+2) -> slot (T+2)%3 = (T-1)%3              (T+2<16)
//             WAR: slot (T-1)%3 was read as af1 by body T-1; those reads
//             retired before body T-1's half1 MFMAs, which precede every
//             wave's arrival at THIS barrier. Cross-wave safe.
//          6. 4 ds_read af0_next <- slot (T+1)%3 half0          (T<15)
//          7. 16 MFMA half0 (af0 x bEven)
//          8. loadB(2T+2)->bEven                                (T<15)
//          9. vmcnt(8)  [completes B(2T+1); leaves stage(T+2)+B(2T+2)]
//             T=14: vmcnt(4); T=15: vmcnt(0)
//         10. 16 MFMA half1 (af1 x bOdd)
// In-order ledger invariant entering body T: {stage(T+1)(4), B(2T)(4)} = 8.
// Slots touched per body: read T%3 (af1), read (T+1)%3 (af0n), write (T-1)%3
//   (stage) — all distinct mod 3.
// out[m][n] = sum_k A[m][k] * W[n][k] + bias[n]
// KIND 0: fused QKV, N=3072; KIND 1: proj, N=1024 (fp32 out).
template<int KIND>
__global__ __launch_bounds__(256, 3)
void gemm_pipe(const unsigned short* __restrict__ A,
               const unsigned short* __restrict__ Wf,
               const float* __restrict__ b0, const float* __restrict__ b1,
               const float* __restrict__ b2,
               unsigned short* __restrict__ oq, unsigned short* __restrict__ okT,
               unsigned short* __restrict__ ovT, float* __restrict__ of)
{
  __shared__ __align__(16) unsigned short lds[24576];   // 3 superbufs x 128x64 bf16

  const int tid  = threadIdx.x;
  const int lane = tid & 63;
  const int wid  = tid >> 6;

  // XCD-aware bijective order: per XCD, (col-group) x (32 A-panels) x (8 cols).
  const int flat  = blockIdx.x;
  const int xcd   = flat & 7;
  const int i     = flat >> 3;
  const int bcg   = i >> 8;
  const int r     = i & 255;
  const int panel = r >> 3;
  const int c     = r & 7;
  const int brow  = (xcd * 32 + panel) * 128;
  const int bcol  = (bcg * 8 + c) * 128;

  // A staging (per 32-k half, r10 mapping): instr o: row = o*64+wid*16+lane/4;
  // dest 16B-slot = lane&3; src slot = (lane&3)^((lane>>3)&3) (XOR swizzle).
  const int srow = wid * 16 + (lane >> 2);
  const int scol = ((lane & 3) ^ ((lane >> 3) & 3)) << 3;
  const unsigned short* a_src = A + (size_t)(brow + srow) * 1024 + scol;
  unsigned short* Ldst = lds + wid * 512;

  const int wm = (wid >> 1) * 64;       // wave tile 64x64
  const int wn = (wid & 1) * 64;
  const int fr = lane & 15;
  const int fg = lane >> 4;
  const int aoff = (wm + fr) * 32 + ((fg ^ ((fr >> 1) & 3)) << 3);

  // B fragment pointer: frag block = ((bcol+wn)>>4 + nt)*32 + k32, 1KB/block.
  const unsigned short* wfp = Wf + ((size_t)((bcol + wn) >> 4) * 32) * 512 + lane * 8;

  const f32x4 fz = {0.f, 0.f, 0.f, 0.f};
  f32x4 acc[4][4];
  #pragma unroll
  for (int mt = 0; mt < 4; ++mt)
    #pragma unroll
    for (int nt = 0; nt < 4; ++nt) acc[mt][nt] = fz;

  // stage supertile T into superbuffer sb (4 gl_lds: 2 halves x 2 instrs)
  auto stage = [&](int T, int sb) {
    unsigned short* d = Ldst + sb * 8192;
    const unsigned short* g = a_src + T * 64;
    gl_lds16(g,              d);
    gl_lds16(g + 65536,      d + 2048);
    gl_lds16(g + 32,         d + 4096);
    gl_lds16(g + 65536 + 32, d + 6144);
  };
  auto loadB = [&](int k32, bf16x8 (&dst)[4]) {
    #pragma unroll
    for (int nt = 0; nt < 4; ++nt)
      dst[nt] = __builtin_bit_cast(bf16x8,
        *(const u32x4*)(wfp + (size_t)k32 * 512 + (size_t)nt * 16384));
  };

  bf16x8 bEven[4], bOdd[4];
  bf16x8 af0A[4], af0B[4], af1[4];

  // prologue: stage(0)->sb0, stage(1)->sb1, loadB(0).
  // vmcnt(8) completes stage(0) [leaves stage(1)+B(0)=8 = loop invariant];
  // barrier publishes stage(0); prefetch af0(supertile 0, half0).
  stage(0, 0); stage(1, 1);
  loadB(0, bEven);
  asm volatile("s_waitcnt vmcnt(8)" ::: "memory");
  __builtin_amdgcn_sched_barrier(0);
  __builtin_amdgcn_s_barrier();
  #pragma unroll
  for (int mt = 0; mt < 4; ++mt)
    af0A[mt] = __builtin_bit_cast(bf16x8, *(const u32x4*)&lds[aoff + mt * 512]);

  auto body = [&](int T, bf16x8 (&af0c)[4], bf16x8 (&af0n)[4]) {
    loadB(2 * T + 1, bOdd);
    {
      const unsigned short* Lb1 = lds + (T % 3) * 8192 + 4096;
      #pragma unroll
      for (int mt = 0; mt < 4; ++mt)
        af1[mt] = __builtin_bit_cast(bf16x8, *(const u32x4*)&Lb1[aoff + mt * 512]);
    }
    asm volatile("s_waitcnt vmcnt(4)" ::: "memory");   // stage(T+1), B(2T) landed
    __builtin_amdgcn_sched_barrier(0);
    if (T < 15) __builtin_amdgcn_s_barrier();          // publishes stage(T+1)
    if (T + 2 < 16) stage(T + 2, (T + 2) % 3);
    if (T < 15) {
      const unsigned short* Lb0 = lds + ((T + 1) % 3) * 8192;
      #pragma unroll
      for (int mt = 0; mt < 4; ++mt)
        af0n[mt] = __builtin_bit_cast(bf16x8, *(const u32x4*)&Lb0[aoff + mt * 512]);
    }
    __builtin_amdgcn_s_setprio(1);
    #pragma unroll
    for (int mt = 0; mt < 4; ++mt)
      #pragma unroll
      for (int nt = 0; nt < 4; ++nt)
        acc[mt][nt] = __builtin_amdgcn_mfma_f32_16x16x32_bf16(af0c[mt], bEven[nt], acc[mt][nt], 0, 0, 0);
    __builtin_amdgcn_s_setprio(0);
    if (T < 15) loadB(2 * T + 2, bEven);
    if (T <= 13)      asm volatile("s_waitcnt vmcnt(8)" ::: "memory");
    else if (T == 14) asm volatile("s_waitcnt vmcnt(4)" ::: "memory");
    else              asm volatile("s_waitcnt vmcnt(0)" ::: "memory");
    __builtin_amdgcn_sched_barrier(0);
    __builtin_amdgcn_s_setprio(1);
    #pragma unroll
    for (int mt = 0; mt < 4; ++mt)
      #pragma unroll
      for (int nt = 0; nt < 4; ++nt)
        acc[mt][nt] = __builtin_amdgcn_mfma_f32_16x16x32_bf16(af1[mt], bOdd[nt], acc[mt][nt], 0, 0, 0);
    __builtin_amdgcn_s_setprio(0);
  };

  for (int T = 0; T < 16; T += 2) {   // static parity: af0A/af0B never runtime-indexed
    body(T,     af0A, af0B);
    body(T + 1, af0B, af0A);
  }

  // ---------------- epilogue ----------------
  const int sec = (KIND == 0) ? (bcol >> 10) : 0;
  const float* bias = (KIND == 1) ? b0 : (sec == 0 ? b0 : (sec == 1 ? b1 : b2));

  #pragma unroll
  for (int nt = 0; nt < 4; ++nt) {
    const int n_glob = bcol + wn + nt * 16 + fr;
    const int nn = (KIND == 0) ? (n_glob & 1023) : n_glob;
    const float bv = bias[nn];
    #pragma unroll
    for (int mt = 0; mt < 4; ++mt) {
      const int m0 = brow + wm + mt * 16 + fg * 4;
      float vals[4];
      #pragma unroll
      for (int r2 = 0; r2 < 4; ++r2) vals[r2] = acc[mt][nt][r2] + bv;

      if (KIND == 0 && sec <= 1) {
        // softmax over the 16 columns (one head's HD), per row.
        // No max-subtraction: |q| <= ~6 -> exp safe in fp32 (validated r9/r10).
        #pragma unroll
        for (int r2 = 0; r2 < 4; ++r2) {
          float e = __expf(vals[r2]);
          float sm = e;
          #pragma unroll
          for (int s = 1; s < 16; s <<= 1) sm += __shfl_xor(sm, s, 64);
          vals[r2] = e * __builtin_amdgcn_rcpf(sm);
        }
      }

      if (KIND == 1) {
        #pragma unroll
        for (int r2 = 0; r2 < 4; ++r2)
          of[(size_t)(m0 + r2) * 1024 + n_glob] = vals[r2];
      } else if (sec == 0) {
        #pragma unroll
        for (int r2 = 0; r2 < 4; ++r2)
          oq[(size_t)(m0 + r2) * 1024 + nn] = f2bf(vals[r2]);
      } else {
        // transposed per head: dst[((b*64+h)*16+d)*4096 + t]
        unsigned short* o = (sec == 1) ? okT : ovT;
        const int bb = m0 >> 12;
        const int t0 = m0 & 4095;
        const int hh = nn >> 4;
        const int dd = nn & 15;
        u16x4 pk;
        pk.x = f2bf(vals[0]); pk.y = f2bf(vals[1]);
        pk.z = f2bf(vals[2]); pk.w = f2bf(vals[3]);
        *(u16x4*)&o[(((size_t)bb * 64 + hh) * 16 + dd) * 4096 + t0] = pk;
      }
    }
  }
}

// ---------------- per-head-PAIR linear-attention middle (r12, kept) ----------------
__global__ __launch_bounds__(256)
void attn_kernel(const unsigned short* __restrict__ qb,
                 const unsigned short* __restrict__ kT,
                 const unsigned short* __restrict__ vT,
                 unsigned short* __restrict__ yb)
{
  const int pair = blockIdx.x;           // b*32 + hp
  const int b    = pair >> 5;
  const int hp   = pair & 31;
  const int tid  = threadIdx.x;
  const int lane = tid & 63;
  const int wid  = tid >> 6;
  const int fr   = lane & 15;
  const int fg   = lane >> 4;

  const unsigned short* kT0 = kT + ((size_t)(b * 64 + hp * 2) * 16) * 4096;
  const unsigned short* vT0 = vT + ((size_t)(b * 64 + hp * 2) * 16) * 4096;
  const unsigned short* kT1 = kT0 + 16 * 4096;
  const unsigned short* vT1 = vT0 + 16 * 4096;

  const u32x4 uz = {0u, 0u, 0u, 0u};
  const f32x4 fz = {0.f, 0.f, 0.f, 0.f};
  const u32x4 uo = {0x3F803F80u, 0x3F803F80u, 0x3F803F80u, 0x3F803F80u};
  const bf16x8 ones = __builtin_bit_cast(bf16x8, uo);

  f32x4 cctx0 = fz, ckc0 = fz, cctx1 = fz, ckc1 = fz;
  #pragma unroll 2
  for (int t0 = wid * 1024; t0 < (wid + 1) * 1024; t0 += 32) {
    const size_t off = (size_t)fr * 4096 + t0 + fg * 8;
    bf16x8 ak0 = __builtin_bit_cast(bf16x8, *(const u32x4*)&kT0[off]);
    bf16x8 bv0 = __builtin_bit_cast(bf16x8, *(const u32x4*)&vT0[off]);
    bf16x8 ak1 = __builtin_bit_cast(bf16x8, *(const u32x4*)&kT1[off]);
    bf16x8 bv1 = __builtin_bit_cast(bf16x8, *(const u32x4*)&vT1[off]);
    cctx0 = __builtin_amdgcn_mfma_f32_16x16x32_bf16(ak0, bv0, cctx0, 0, 0, 0);
    ckc0  = __builtin_amdgcn_mfma_f32_16x16x32_bf16(ak0, ones, ckc0, 0, 0, 0);
    cctx1 = __builtin_amdgcn_mfma_f32_16x16x32_bf16(ak1, bv1, cctx1, 0, 0, 0);
    ckc1  = __builtin_amdgcn_mfma_f32_16x16x32_bf16(ak1, ones, ckc1, 0, 0, 0);
  }

  __shared__ float red[4][2][16][16];
  __shared__ float kcr[4][2][16];
  __shared__ float ctxf[2][16][16];
  __shared__ float kcf[2][16];

  #pragma unroll
  for (int r = 0; r < 4; ++r) {
    red[wid][0][fg * 4 + r][fr] = cctx0[r];
    red[wid][1][fg * 4 + r][fr] = cctx1[r];
  }
  if (fr == 0) {
    #pragma unroll
    for (int r = 0; r < 4; ++r) {
      kcr[wid][0][fg * 4 + r] = ckc0[r];
      kcr[wid][1][fg * 4 + r] = ckc1[r];
    }
  }
  __syncthreads();
  {
    const int d = (tid >> 4) & 15, e = tid & 15;
    #pragma unroll
    for (int hh = 0; hh < 2; ++hh)
      ctxf[hh][d][e] = red[0][hh][d][e] + red[1][hh][d][e] + red[2][hh][d][e] + red[3][hh][d][e];
    if (tid < 32) {
      const int hh = tid >> 4, dd = tid & 15;
      kcf[hh][dd] = kcr[0][hh][dd] + kcr[1][hh][dd] + kcr[2][hh][dd] + kcr[3][hh][dd];
    }
  }
  __syncthreads();

  // Block-diagonal B fragments: k index = fg*8+j spans head0 (k<16) / head1 (k>=16).
  bf16x8 bctx0 = __builtin_bit_cast(bf16x8, uz);
  bf16x8 bctx1 = __builtin_bit_cast(bf16x8, uz);
  bf16x8 bkc0  = __builtin_bit_cast(bf16x8, uz);
  bf16x8 bkc1  = __builtin_bit_cast(bf16x8, uz);
  if (fg < 2) {
    #pragma unroll
    for (int j = 0; j < 8; ++j) {
      const int d = fg * 8 + j;
      bctx0[j] = (__bf16)ctxf[0][d][fr];
      bkc0[j]  = (__bf16)kcf[0][d];
    }
  } else {
    #pragma unroll
    for (int j = 0; j < 8; ++j) {
      const int d = (fg - 2) * 8 + j;
      bctx1[j] = (__bf16)ctxf[1][d][fr];
      bkc1[j]  = (__bf16)kcf[1][d];
    }
  }

  const size_t cbase = (size_t)b * 4096 * 1024 + (size_t)hp * 32;

  for (int step = 0; step < 64; ++step) {
    const int t0 = step * 64 + wid * 16;
    bf16x8 af = __builtin_bit_cast(bf16x8,
        *(const u32x4*)&qb[cbase + (size_t)(t0 + fr) * 1024 + fg * 8]);
    f32x4 cy0 = __builtin_amdgcn_mfma_f32_16x16x32_bf16(af, bctx0, fz, 0, 0, 0);
    f32x4 cy1 = __builtin_amdgcn_mfma_f32_16x16x32_bf16(af, bctx1, fz, 0, 0, 0);
    f32x4 cd0 = __builtin_amdgcn_mfma_f32_16x16x32_bf16(af, bkc0,  fz, 0, 0, 0);
    f32x4 cd1 = __builtin_amdgcn_mfma_f32_16x16x32_bf16(af, bkc1,  fz, 0, 0, 0);
    #pragma unroll
    for (int r = 0; r < 4; ++r) {
      const int t = t0 + fg * 4 + r;
      const size_t o = cbase + (size_t)t * 1024;
      yb[o + fr]      = f2bf(cy0[r] * __builtin_amdgcn_rcpf(cd0[r]));
      yb[o + 16 + fr] = f2bf(cy1[r] * __builtin_amdgcn_rcpf(cd1[r]));
    }
  }
}

// ---------------- launch ----------------
extern "C" void kernel_launch(void* const* d_in, const int* in_sizes, int n_in,
                              void* d_out, int out_size, void* d_ws, size_t ws_size,
                              hipStream_t stream)
{
  (void)in_sizes; (void)n_in; (void)out_size; (void)ws_size;
  const float* x  = (const float*)d_in[0];
  const float* Wq = (const float*)d_in[1];
  const float* bq = (const float*)d_in[2];
  const float* Wk = (const float*)d_in[3];
  const float* bk = (const float*)d_in[4];
  const float* Wv = (const float*)d_in[5];
  const float* bv = (const float*)d_in[6];
  const float* Wp = (const float*)d_in[7];
  const float* bp = (const float*)d_in[8];

  char* ws = (char*)d_ws;
  // requires ws_size >= 276,824,064 bytes
  unsigned short* xb  = (unsigned short*)(ws);              // 67108864 B; reused as yb
  unsigned short* wb  = (unsigned short*)(ws + 67108864);   // 4 x 2097152 B, frag-packed
  unsigned short* qb  = (unsigned short*)(ws + 75497472);   // 67108864 B
  unsigned short* kTb = (unsigned short*)(ws + 142606336);  // 67108864 B
  unsigned short* vTb = (unsigned short*)(ws + 209715200);  // 67108864 B

  cvt_all<<<4096, 256, 0, stream>>>(x, Wq, Wk, Wv, Wp, xb, wb);

  gemm_pipe<0><<<6144, 256, 0, stream>>>(xb, wb, bq, bk, bv, qb, kTb, vTb, nullptr);

  attn_kernel<<<256, 256, 0, stream>>>(qb, kTb, vTb, xb /* = yb */);

  gemm_pipe<1><<<2048, 256, 0, stream>>>(xb /* yb */, wb + 3145728, bp, bp, bp,
                                         nullptr, nullptr, nullptr, (float*)d_out);
}